// Round 1
// baseline (164.757 us; speedup 1.0000x reference)
//
#include <hip/hip_runtime.h>

#define DIOU_EPS 1e-7f

constexpr int BLOCK = 256;              // 4 waves
constexpr int BPC   = 8;                // blocks per CU (VGPR<=64 -> 8 waves/SIMD ok)
constexpr int GRID  = 256 * BPC;        // 2048 persistent blocks -> 32 waves/CU
constexpr int VPT   = 4;                // elements per thread per tile
constexpr int TILE  = BLOCK * VPT;      // 1024 elements per block-tile

__device__ __forceinline__ float rcp_fast(float x) {
    return __builtin_amdgcn_rcpf(x);    // v_rcp_f32 ~1ulp; passed absmax 0.0 previously
}

__device__ __forceinline__ float diou_elem(float4 a, float4 b, int m) {
    float a1 = (a.z - a.x) * (a.w - a.y);
    float a2 = (b.z - b.x) * (b.w - b.y);

    float iw = fmaxf(fminf(a.z, b.z) - fmaxf(a.x, b.x), 0.0f);
    float ih = fmaxf(fminf(a.w, b.w) - fmaxf(a.y, b.y), 0.0f);
    float inter = iw * ih;
    float uni = a1 + a2 - inter;

    float wc = fmaxf(a.z, b.z) - fminf(a.x, b.x);
    float hc = fmaxf(a.w, b.w) - fminf(a.y, b.y);
    float area_c = wc * hc;

    float dx = (a.x + a.z - b.x - b.z) * 0.5f;
    float dy = (a.y + a.w - b.y - b.w) * 0.5f;
    float d2 = dx * dx + dy * dy;
    float diag2 = wc * wc + hc * hc;

    // loss = 1 - diou = 2 - inter/uni - uni/area_c + d2/(diag2+eps)
    float loss = 2.0f - inter * rcp_fast(uni)
                      - uni   * rcp_fast(area_c)
                      + d2    * rcp_fast(diag2 + DIOU_EPS);

    return (m != 0) ? loss : 0.0f;
}

__global__ __launch_bounds__(BLOCK, BPC) void diou_partial_kernel(
    const float4* __restrict__ boxes1,
    const float4* __restrict__ boxes2,
    const int* __restrict__ mask,
    float* __restrict__ ws,
    int n)
{
    const int t    = threadIdx.x;
    const int lane = t & 63;
    const int wave = t >> 6;
    const int nfull = n / TILE;

    float acc = 0.0f;

    // Wave-coalesced layout: wave owns 256 consecutive elements of the tile;
    // lane l reads element waveBase + j*64 + l  ->  every dwordx4 is a
    // contiguous 1 KiB/wave transaction, per-j imm offset = j*1024 B (fits imm13).
    for (int tb = blockIdx.x; tb < nfull; tb += GRID) {
        const int base = tb * TILE + wave * (64 * VPT) + lane;   // element index

        float4 A[VPT], B[VPT];
        int    M[VPT];
        #pragma unroll
        for (int j = 0; j < VPT; ++j) A[j] = boxes1[base + j * 64];
        #pragma unroll
        for (int j = 0; j < VPT; ++j) B[j] = boxes2[base + j * 64];
        #pragma unroll
        for (int j = 0; j < VPT; ++j) M[j] = mask[base + j * 64]; // coalesced dword

        #pragma unroll
        for (int j = 0; j < VPT; ++j) acc += diou_elem(A[j], B[j], M[j]);
    }

    // tail (empty for n = 4,194,304; kept for generality)
    for (int i = nfull * TILE + blockIdx.x * BLOCK + t; i < n;
         i += GRID * BLOCK)
        acc += diou_elem(boxes1[i], boxes2[i], mask[i]);

    // block reduce -> one partial per block, no global atomics
    #pragma unroll
    for (int off = 32; off > 0; off >>= 1)
        acc += __shfl_down(acc, off, 64);

    __shared__ float wsum[BLOCK / 64];
    if (lane == 0) wsum[wave] = acc;
    __syncthreads();
    if (t == 0) ws[blockIdx.x] = wsum[0] + wsum[1] + wsum[2] + wsum[3];
}

__global__ __launch_bounds__(BLOCK) void finalize_kernel(
    const float* __restrict__ ws,
    const int* __restrict__ num_boxes,
    float* __restrict__ out)
{
    const int t = threadIdx.x;
    float a = 0.0f;
    #pragma unroll
    for (int i = 0; i < GRID / BLOCK; ++i) a += ws[i * BLOCK + t];

    #pragma unroll
    for (int off = 32; off > 0; off >>= 1)
        a += __shfl_down(a, off, 64);

    __shared__ float wsum[BLOCK / 64];
    if ((t & 63) == 0) wsum[t >> 6] = a;
    __syncthreads();
    if (t == 0)
        out[0] = (wsum[0] + wsum[1] + wsum[2] + wsum[3]) / (float)num_boxes[0];
}

extern "C" void kernel_launch(void* const* d_in, const int* in_sizes, int n_in,
                              void* d_out, int out_size, void* d_ws, size_t ws_size,
                              hipStream_t stream) {
    const float4* boxes1 = (const float4*)d_in[0];   // (B,Q,4) f32
    const float4* boxes2 = (const float4*)d_in[1];   // (B,Q,4) f32
    const int* mask = (const int*)d_in[2];           // (B,Q) bool -> int32
    const int* num_boxes = (const int*)d_in[3];      // scalar

    float* out = (float*)d_out;
    float* partials = (float*)d_ws;                  // GRID floats of scratch (8 KiB)
    int n = in_sizes[2];                             // B*Q pairs

    diou_partial_kernel<<<GRID, BLOCK, 0, stream>>>(boxes1, boxes2, mask, partials, n);
    finalize_kernel<<<1, BLOCK, 0, stream>>>(partials, num_boxes, out);
}

// Round 6
// 151.809 us; speedup vs baseline: 1.0853x; 1.0853x over previous
//
#include <hip/hip_runtime.h>

#define DIOU_EPS 1e-7f

constexpr int BLOCK = 256;              // 4 waves
constexpr int BPC   = 8;                // blocks per CU (VGPR<=64 -> 8 waves/SIMD)
constexpr int GRID  = 256 * BPC;        // 2048 persistent blocks -> 32 waves/CU
constexpr int VPT   = 4;                // elements per thread per tile
constexpr int TILE  = BLOCK * VPT;      // 1024 elements per block-tile

// native vector type: __builtin_nontemporal_load rejects HIP_vector_type,
// accepts ext_vector_type. Bit-identical layout to float4.
typedef float vfloat4 __attribute__((ext_vector_type(4)));

__device__ __forceinline__ float rcp_fast(float x) {
    return __builtin_amdgcn_rcpf(x);    // v_rcp_f32 ~1ulp; absmax 0.0 on harness
}

__device__ __forceinline__ float diou_elem(vfloat4 a, vfloat4 b, int m) {
    // lanes: [0]=x1 [1]=y1 [2]=x2 [3]=y2
    float a1 = (a[2] - a[0]) * (a[3] - a[1]);
    float a2 = (b[2] - b[0]) * (b[3] - b[1]);

    float iw = fmaxf(fminf(a[2], b[2]) - fmaxf(a[0], b[0]), 0.0f);
    float ih = fmaxf(fminf(a[3], b[3]) - fmaxf(a[1], b[1]), 0.0f);
    float inter = iw * ih;
    float uni = a1 + a2 - inter;

    float wc = fmaxf(a[2], b[2]) - fminf(a[0], b[0]);
    float hc = fmaxf(a[3], b[3]) - fminf(a[1], b[1]);
    float area_c = wc * hc;

    float dx = (a[0] + a[2] - b[0] - b[2]) * 0.5f;
    float dy = (a[1] + a[3] - b[1] - b[3]) * 0.5f;
    float d2 = dx * dx + dy * dy;
    float diag2 = wc * wc + hc * hc;

    // loss = 1 - diou = 2 - inter/uni - uni/area_c + d2/(diag2+eps)
    float loss = 2.0f - inter * rcp_fast(uni)
                      - uni   * rcp_fast(area_c)
                      + d2    * rcp_fast(diag2 + DIOU_EPS);

    return (m != 0) ? loss : 0.0f;
}

__global__ __launch_bounds__(BLOCK, BPC) void diou_partial_kernel(
    const vfloat4* __restrict__ boxes1,
    const vfloat4* __restrict__ boxes2,
    const int* __restrict__ mask,
    float* __restrict__ ws,
    int n)
{
    const int t    = threadIdx.x;
    const int lane = t & 63;
    const int wave = t >> 6;
    const int nfull = n / TILE;

    float acc = 0.0f;

    // Wave-coalesced: lane l reads element waveBase + j*64 + l -> every dwordx4
    // is a contiguous 1 KiB/wave transaction. SINGLE CHANGE UNDER TEST:
    // non-temporal loads (nt bit) on all three read-once streams, probing
    // whether the ~2.8 TB/s wall is the L3 allocation/probe path.
    for (int tb = blockIdx.x; tb < nfull; tb += GRID) {
        const int base = tb * TILE + wave * (64 * VPT) + lane;   // element index

        vfloat4 A[VPT], B[VPT];
        int     M[VPT];
        #pragma unroll
        for (int j = 0; j < VPT; ++j)
            A[j] = __builtin_nontemporal_load(&boxes1[base + j * 64]);
        #pragma unroll
        for (int j = 0; j < VPT; ++j)
            B[j] = __builtin_nontemporal_load(&boxes2[base + j * 64]);
        #pragma unroll
        for (int j = 0; j < VPT; ++j)
            M[j] = __builtin_nontemporal_load(&mask[base + j * 64]);

        #pragma unroll
        for (int j = 0; j < VPT; ++j) acc += diou_elem(A[j], B[j], M[j]);
    }

    // tail (empty for n = 4,194,304; kept for generality)
    for (int i = nfull * TILE + blockIdx.x * BLOCK + t; i < n;
         i += GRID * BLOCK)
        acc += diou_elem(boxes1[i], boxes2[i], mask[i]);

    // block reduce -> one partial per block, no global atomics
    #pragma unroll
    for (int off = 32; off > 0; off >>= 1)
        acc += __shfl_down(acc, off, 64);

    __shared__ float wsum[BLOCK / 64];
    if (lane == 0) wsum[wave] = acc;
    __syncthreads();
    if (t == 0) ws[blockIdx.x] = wsum[0] + wsum[1] + wsum[2] + wsum[3];
}

__global__ __launch_bounds__(BLOCK) void finalize_kernel(
    const float* __restrict__ ws,
    const int* __restrict__ num_boxes,
    float* __restrict__ out)
{
    const int t = threadIdx.x;
    float a = 0.0f;
    #pragma unroll
    for (int i = 0; i < GRID / BLOCK; ++i) a += ws[i * BLOCK + t];

    #pragma unroll
    for (int off = 32; off > 0; off >>= 1)
        a += __shfl_down(a, off, 64);

    __shared__ float wsum[BLOCK / 64];
    if ((t & 63) == 0) wsum[t >> 6] = a;
    __syncthreads();
    if (t == 0)
        out[0] = (wsum[0] + wsum[1] + wsum[2] + wsum[3]) / (float)num_boxes[0];
}

extern "C" void kernel_launch(void* const* d_in, const int* in_sizes, int n_in,
                              void* d_out, int out_size, void* d_ws, size_t ws_size,
                              hipStream_t stream) {
    const vfloat4* boxes1 = (const vfloat4*)d_in[0];   // (B,Q,4) f32
    const vfloat4* boxes2 = (const vfloat4*)d_in[1];   // (B,Q,4) f32
    const int* mask = (const int*)d_in[2];             // (B,Q) bool -> int32
    const int* num_boxes = (const int*)d_in[3];        // scalar

    float* out = (float*)d_out;
    float* partials = (float*)d_ws;                    // GRID floats (8 KiB)
    int n = in_sizes[2];                               // B*Q pairs

    diou_partial_kernel<<<GRID, BLOCK, 0, stream>>>(boxes1, boxes2, mask, partials, n);
    finalize_kernel<<<1, BLOCK, 0, stream>>>(partials, num_boxes, out);
}

// Round 11
// 150.019 us; speedup vs baseline: 1.0982x; 1.0119x over previous
//
#include <hip/hip_runtime.h>

#define DIOU_EPS 1e-7f

constexpr int BLOCK = 256;              // 4 waves
constexpr int BPC   = 5;                // blocks/CU cap -> ~100 VGPR budget
constexpr int GRID  = 2048;             // == nfull: exactly ONE tile per block
constexpr int VPT   = 8;                // elements per thread per tile (18 loads in flight)
constexpr int TILE  = BLOCK * VPT;      // 2048 elements per block-tile

// native vector type: __builtin_nontemporal_load rejects HIP_vector_type,
// accepts ext_vector_type. Bit-identical layout to float4.
typedef float vfloat4 __attribute__((ext_vector_type(4)));

__device__ __forceinline__ float rcp_fast(float x) {
    return __builtin_amdgcn_rcpf(x);    // v_rcp_f32 ~1ulp; absmax 0.0 on harness
}

__device__ __forceinline__ float diou_elem(vfloat4 a, vfloat4 b, int m) {
    // lanes: [0]=x1 [1]=y1 [2]=x2 [3]=y2
    float a1 = (a[2] - a[0]) * (a[3] - a[1]);
    float a2 = (b[2] - b[0]) * (b[3] - b[1]);

    float iw = fmaxf(fminf(a[2], b[2]) - fmaxf(a[0], b[0]), 0.0f);
    float ih = fmaxf(fminf(a[3], b[3]) - fmaxf(a[1], b[1]), 0.0f);
    float inter = iw * ih;
    float uni = a1 + a2 - inter;

    float wc = fmaxf(a[2], b[2]) - fminf(a[0], b[0]);
    float hc = fmaxf(a[3], b[3]) - fminf(a[1], b[1]);
    float area_c = wc * hc;

    float dx = (a[0] + a[2] - b[0] - b[2]) * 0.5f;
    float dy = (a[1] + a[3] - b[1] - b[3]) * 0.5f;
    float d2 = dx * dx + dy * dy;
    float diag2 = wc * wc + hc * hc;

    // loss = 1 - diou = 2 - inter/uni - uni/area_c + d2/(diag2+eps)
    float loss = 2.0f - inter * rcp_fast(uni)
                      - uni   * rcp_fast(area_c)
                      + d2    * rcp_fast(diag2 + DIOU_EPS);

    return (m != 0) ? loss : 0.0f;
}

__global__ __launch_bounds__(BLOCK, BPC) void diou_partial_kernel(
    const vfloat4* __restrict__ boxes1,
    const vfloat4* __restrict__ boxes2,
    const int* __restrict__ mask,
    float* __restrict__ ws,
    int n)
{
    const int t    = threadIdx.x;
    const int lane = t & 63;
    const int wave = t >> 6;
    const int nfull = n / TILE;

    float acc = 0.0f;

    // Wave-coalesced nt loads: lane l reads element waveBase + j*64 + l ->
    // every dwordx4 is a contiguous 1 KiB/wave nt transaction.
    // SINGLE CHANGE UNDER TEST (vs round 6): VPT 4->8, one tile per block ->
    // 18 loads issued per thread before any compute (MLP probe: C vs D).
    for (int tb = blockIdx.x; tb < nfull; tb += GRID) {
        const int base = tb * TILE + wave * (64 * VPT) + lane;   // element index

        vfloat4 A[VPT], B[VPT];
        int     M[VPT];
        #pragma unroll
        for (int j = 0; j < VPT; ++j)
            A[j] = __builtin_nontemporal_load(&boxes1[base + j * 64]);
        #pragma unroll
        for (int j = 0; j < VPT; ++j)
            B[j] = __builtin_nontemporal_load(&boxes2[base + j * 64]);
        #pragma unroll
        for (int j = 0; j < VPT; ++j)
            M[j] = __builtin_nontemporal_load(&mask[base + j * 64]);

        #pragma unroll
        for (int j = 0; j < VPT; ++j) acc += diou_elem(A[j], B[j], M[j]);
    }

    // tail (empty for n = 4,194,304; kept for generality)
    for (int i = nfull * TILE + blockIdx.x * BLOCK + t; i < n;
         i += GRID * BLOCK)
        acc += diou_elem(boxes1[i], boxes2[i], mask[i]);

    // block reduce -> one partial per block, no global atomics
    #pragma unroll
    for (int off = 32; off > 0; off >>= 1)
        acc += __shfl_down(acc, off, 64);

    __shared__ float wsum[BLOCK / 64];
    if (lane == 0) wsum[wave] = acc;
    __syncthreads();
    if (t == 0) ws[blockIdx.x] = wsum[0] + wsum[1] + wsum[2] + wsum[3];
}

__global__ __launch_bounds__(BLOCK) void finalize_kernel(
    const float* __restrict__ ws,
    const int* __restrict__ num_boxes,
    float* __restrict__ out)
{
    const int t = threadIdx.x;
    float a = 0.0f;
    #pragma unroll
    for (int i = 0; i < GRID / BLOCK; ++i) a += ws[i * BLOCK + t];

    #pragma unroll
    for (int off = 32; off > 0; off >>= 1)
        a += __shfl_down(a, off, 64);

    __shared__ float wsum[BLOCK / 64];
    if ((t & 63) == 0) wsum[t >> 6] = a;
    __syncthreads();
    if (t == 0)
        out[0] = (wsum[0] + wsum[1] + wsum[2] + wsum[3]) / (float)num_boxes[0];
}

extern "C" void kernel_launch(void* const* d_in, const int* in_sizes, int n_in,
                              void* d_out, int out_size, void* d_ws, size_t ws_size,
                              hipStream_t stream) {
    const vfloat4* boxes1 = (const vfloat4*)d_in[0];   // (B,Q,4) f32
    const vfloat4* boxes2 = (const vfloat4*)d_in[1];   // (B,Q,4) f32
    const int* mask = (const int*)d_in[2];             // (B,Q) bool -> int32
    const int* num_boxes = (const int*)d_in[3];        // scalar

    float* out = (float*)d_out;
    float* partials = (float*)d_ws;                    // GRID floats (8 KiB)
    int n = in_sizes[2];                               // B*Q pairs

    diou_partial_kernel<<<GRID, BLOCK, 0, stream>>>(boxes1, boxes2, mask, partials, n);
    finalize_kernel<<<1, BLOCK, 0, stream>>>(partials, num_boxes, out);
}